// Round 4
// baseline (220.214 us; speedup 1.0000x reference)
//
#include <hip/hip_runtime.h>
#include <hip/hip_bf16.h>
#include <stdint.h>

// Problem constants: x[16,256,64,64] f32; fc1[65,256]; fc2[1024,65]; fc2_b[1024];
// weight[4,256,256,3,3]; out[16,256,64,64] f32.

typedef __bf16 bf16x8 __attribute__((ext_vector_type(8)));
typedef float  f32x4  __attribute__((ext_vector_type(4)));

__device__ __forceinline__ unsigned short f2bf(float f) {
  union { float f; unsigned u; } v; v.f = f;
  return (unsigned short)((v.u + 0x7FFFu + ((v.u >> 16) & 1u)) >> 16);
}

__device__ __forceinline__ void gload16(const void* g, void* l) {
  __builtin_amdgcn_global_load_lds(
      (const __attribute__((address_space(1))) void*)g,
      (__attribute__((address_space(3))) void*)l, 16, 0, 0);
}

#define WAIT_VM0() do { __builtin_amdgcn_sched_barrier(0); \
  asm volatile("s_waitcnt vmcnt(0)" ::: "memory"); \
  __builtin_amdgcn_sched_barrier(0); } while (0)
#define BARRIER_PIN() do { __builtin_amdgcn_s_barrier(); \
  __builtin_amdgcn_sched_barrier(0); } while (0)

// ---------------- Kernel A: pooling + NCHW f32 -> NHWC bf16 ----------------
// v2: block = one (b, y) row, all 256 channels. Packed-pair LDS transpose;
// global writes are wave-contiguous 8KB (fully coalesced).
// grid: 16*64 = 1024 blocks, 256 threads
__global__ __launch_bounds__(256) void k_prep(
    const float* __restrict__ x, unsigned short* __restrict__ xn,
    float* __restrict__ pooled_sum) {
  const int bx = blockIdx.x;
  const int y  = bx & 63;
  const int b  = bx >> 6;
  const int t  = threadIdx.x;
  const int c2 = t & 127;   // channel pair index (covers ch 2*c2, 2*c2+1)
  const int xh = t >> 7;    // x half (0..1), 32 x each

  const float4* r0 = (const float4*)(x + (((size_t)(b * 256 + 2 * c2    ) * 64 + y) * 64 + xh * 32));
  const float4* r1 = (const float4*)(x + (((size_t)(b * 256 + 2 * c2 + 1) * 64 + y) * 64 + xh * 32));

  __shared__ unsigned int tile[64][132];   // [x][c2] packed (lo=even ch, hi=odd ch)

  float s0 = 0.f, s1 = 0.f;
#pragma unroll
  for (int i = 0; i < 8; ++i) {
    float4 a0 = r0[i], a1 = r1[i];
    s0 += a0.x + a0.y + a0.z + a0.w;
    s1 += a1.x + a1.y + a1.z + a1.w;
    const int xb = xh * 32 + i * 4;
    tile[xb + 0][c2] = (unsigned)f2bf(a0.x) | ((unsigned)f2bf(a1.x) << 16);
    tile[xb + 1][c2] = (unsigned)f2bf(a0.y) | ((unsigned)f2bf(a1.y) << 16);
    tile[xb + 2][c2] = (unsigned)f2bf(a0.z) | ((unsigned)f2bf(a1.z) << 16);
    tile[xb + 3][c2] = (unsigned)f2bf(a0.w) | ((unsigned)f2bf(a1.w) << 16);
  }
  atomicAdd(&pooled_sum[b * 256 + 2 * c2    ], s0);
  atomicAdd(&pooled_sum[b * 256 + 2 * c2 + 1], s1);
  __syncthreads();

  const int p = t >> 2, q = t & 3;           // p: x pos, q: 64-ch quarter
  const uint4* ls = (const uint4*)&tile[p][q * 32];
  uint4* gd = (uint4*)(xn + ((size_t)((b * 64 + y) * 64 + p) * 256 + q * 64));
#pragma unroll
  for (int i = 0; i < 8; ++i) gd[i] = ls[i];
}

// ---------------- Kernel B1: fc1 -> relu -> fc2 -> softmax/T -> prob ----------------
__global__ __launch_bounds__(256) void k_fc(
    const float* __restrict__ pooled_sum,
    const float* __restrict__ fc1, const float* __restrict__ fc2,
    const float* __restrict__ fc2b, float* __restrict__ prob) {
  const int b = blockIdx.x, t = threadIdx.x;
  __shared__ float p[256];
  __shared__ float h[72];
  __shared__ float yv[1024];
  p[t] = pooled_sum[b * 256 + t] * (1.0f / 4096.0f);
  __syncthreads();
  if (t < 65) {
    float s = 0.f;
    for (int c = 0; c < 256; ++c) s += p[c] * fc1[t * 256 + c];
    h[t] = fmaxf(s, 0.f);
  }
  __syncthreads();
  for (int m = t; m < 1024; m += 256) {
    float s = fc2b[m];
    for (int j = 0; j < 65; ++j) s += h[j] * fc2[m * 65 + j];
    yv[m] = s;
  }
  __syncthreads();
  const float invT = 1.0f / 30.0f;
  float e0 = yv[t] * invT, e1 = yv[256 + t] * invT, e2 = yv[512 + t] * invT, e3 = yv[768 + t] * invT;
  float mx = fmaxf(fmaxf(e0, e1), fmaxf(e2, e3));
  float x0 = expf(e0 - mx), x1 = expf(e1 - mx), x2 = expf(e2 - mx), x3 = expf(e3 - mx);
  float r = 1.0f / (x0 + x1 + x2 + x3);
  prob[(b * 4 + 0) * 256 + t] = x0 * r;
  prob[(b * 4 + 1) * 256 + t] = x1 * r;
  prob[(b * 4 + 2) * 256 + t] = x2 * r;
  prob[(b * 4 + 3) * 256 + t] = x3 * r;
}

// ---------------- Kernel B2: aggT[b][tap][o][c] bf16 = sum_k prob*weight ----------------
__global__ __launch_bounds__(256) void k_agg(
    const float* __restrict__ weight, const float* __restrict__ prob,
    unsigned short* __restrict__ aggT) {
  const int o = blockIdx.x, t = threadIdx.x;
  __shared__ float w[4][2304];
#pragma unroll
  for (int k = 0; k < 4; ++k) {
    const float4* src = (const float4*)(weight + (size_t)(k * 256 + o) * 2304);
    float4* dst = (float4*)w[k];
    for (int j = t; j < 576; j += 256) dst[j] = src[j];
  }
  __syncthreads();
  const int c = t;
  float wv[4][9];
#pragma unroll
  for (int k = 0; k < 4; ++k)
#pragma unroll
    for (int tap = 0; tap < 9; ++tap) wv[k][tap] = w[k][c * 9 + tap];
  for (int b = 0; b < 16; ++b) {
    float p0 = prob[(b * 4 + 0) * 256 + o];
    float p1 = prob[(b * 4 + 1) * 256 + o];
    float p2 = prob[(b * 4 + 2) * 256 + o];
    float p3 = prob[(b * 4 + 3) * 256 + o];
#pragma unroll
    for (int tap = 0; tap < 9; ++tap) {
      float vv = p0 * wv[0][tap] + p1 * wv[1][tap] + p2 * wv[2][tap] + p3 * wv[3][tap];
      aggT[((size_t)(b * 9 + tap) * 256 + o) * 256 + c] = f2bf(vv);
    }
  }
}

// ---------------- Kernel C: per-sample implicit-GEMM conv ----------------
// v3: W in REGISTERS (per-wave direct global->reg B-fragments, 1-tap-deep
// double buffer) -> no per-tap barriers at all. X tile double-buffered in
// LDS (64KB), staged via gload_lds one c-chunk ahead; 5 barriers total.
// Tile: 128 pixels x 128 ochans, 4 waves (2x2), 16x16x32 bf16 MFMA.
// grid: 16 b * 32 ytile * 2 otile = 1024 blocks, 256 threads
__global__ __launch_bounds__(256, 2) void k_conv(
    const unsigned short* __restrict__ xn,
    const unsigned short* __restrict__ aggT,
    const unsigned short* __restrict__ zpage,
    float* __restrict__ out) {
  // XCD-aware bijective swizzle (1024 = 8 * 128): each XCD owns 2 samples.
  const int bx0 = blockIdx.x;
  const int bx  = (bx0 & 7) * 128 + (bx0 >> 3);
  const int ot = bx & 1;
  const int yt = (bx >> 1) & 31;
  const int b  = bx >> 6;
  const int y0 = yt * 2;
  const int o0 = ot * 128;
  const int t    = threadIdx.x;
  const int lane = t & 63;
  const int l15  = lane & 15;
  const int lg   = lane >> 4;
  const int wid  = t >> 6;
  const int wm   = wid >> 1;   // pixel row of wave (0..1)
  const int wn   = wid & 1;    // ochan half (0..1)

  __shared__ unsigned short xbuf[2][256 * 64];   // 2 x 32 KiB, double buffer

  const f32x4 vzero = {0.f, 0.f, 0.f, 0.f};
  const bf16x8 bzero = {};
  f32x4 acc[4][4];
#pragma unroll
  for (int i = 0; i < 4; ++i)
#pragma unroll
    for (int j = 0; j < 4; ++j) acc[i][j] = vzero;

  const unsigned short* xb = xn + (size_t)b * (64 * 64 * 256);
  const unsigned short* ab = aggT + (size_t)b * (9 * 256 * 256) + (size_t)o0 * 256;
  // per-lane W base: B-frag element (nf,ku,i) = aggT[och = o0+wn*64+nf*16+l15]
  //                                                 [ch  = c0+ku*32+lg*8+i]
  const unsigned short* wbase = ab + (size_t)(wn * 64 + l15) * 256 + lg * 8;

  auto stageX = [&](int buf, int cc) {
    const int c0s = cc * 64;
#pragma unroll
    for (int i = 0; i < 8; ++i) {
      int u = t + i * 256;
      int pos = u >> 3, s = u & 7;
      int rr = pos >> 6, xc = pos & 63;
      int yy = y0 - 1 + rr;
      int sp = (s ^ (pos & 7)) * 8;
      const unsigned short* src = (yy >= 0 && yy < 64)
          ? xb + ((size_t)yy * 64 + xc) * 256 + (c0s + sp)
          : zpage + ((u & 127) * 8);
      gload16(src, &xbuf[buf][u * 8]);
    }
  };

  stageX(0, 0);
  WAIT_VM0();
  BARRIER_PIN();

  for (int cc = 0; cc < 4; ++cc) {
    const int c0 = cc * 64;
    const unsigned short* xcur = xbuf[cc & 1];
    if (cc < 3) {                      // prefetch next X chunk; drained at loop bottom
      stageX((cc + 1) & 1, cc + 1);
      __builtin_amdgcn_sched_barrier(0);
    }

    bf16x8 bfrag[2][8];                // [tap parity][nf*2+ku] -- static idx via unroll
#pragma unroll
    for (int nf = 0; nf < 4; ++nf)
#pragma unroll
      for (int ku = 0; ku < 2; ++ku)
        bfrag[0][nf * 2 + ku] = *(const bf16x8*)(wbase + nf * 4096 + c0 + ku * 32);

#pragma unroll
    for (int tap = 0; tap < 9; ++tap) {
      if (tap < 8) {                   // prefetch B[tap+1] into other reg set
        const unsigned short* wt = wbase + (size_t)(tap + 1) * 65536 + c0;
#pragma unroll
        for (int nf = 0; nf < 4; ++nf)
#pragma unroll
          for (int ku = 0; ku < 2; ++ku)
            bfrag[(tap + 1) & 1][nf * 2 + ku] = *(const bf16x8*)(wt + nf * 4096 + ku * 32);
      }
      const int kh = tap / 3;
      const int d  = tap % 3 - 1;
      const int prow = (wm + kh) * 64;
#pragma unroll
      for (int ku = 0; ku < 2; ++ku) {
        bf16x8 av[4];
#pragma unroll
        for (int mf = 0; mf < 4; ++mf) {
          int xsrc = mf * 16 + l15 + d;
          bool valid = (xsrc >= 0) && (xsrc < 64);
          int xcl = min(max(xsrc, 0), 63);
          int pos = prow + xcl;
          int su = (ku * 4 + lg) ^ (pos & 7);
          av[mf] = *(const bf16x8*)&xcur[pos * 64 + su * 8];
          if (!valid) av[mf] = bzero;  // column halo -> 0
        }
        __builtin_amdgcn_s_setprio(1);
#pragma unroll
        for (int mf = 0; mf < 4; ++mf)
#pragma unroll
          for (int nf = 0; nf < 4; ++nf)
            acc[mf][nf] = __builtin_amdgcn_mfma_f32_16x16x32_bf16(
                av[mf], bfrag[tap & 1][nf * 2 + ku], acc[mf][nf], 0, 0, 0);
        __builtin_amdgcn_s_setprio(0);
      }
    }
    WAIT_VM0();      // X(cc+1) gload_lds issued ~1 chunk ago -> instant; publishes LDS
    BARRIER_PIN();   // all waves done reading xcur before it is overwritten next iter
  }

  // epilogue: D row = pixel = (lane>>4)*4 + reg, col = ochan = lane&15
  const int yrow = y0 + wm;
#pragma unroll
  for (int nf = 0; nf < 4; ++nf) {
    int och = o0 + wn * 64 + nf * 16 + l15;
    float* op = out + ((size_t)(b * 256 + och) * 4096) + yrow * 64;
#pragma unroll
    for (int mf = 0; mf < 4; ++mf) {
      int xcb = mf * 16 + lg * 4;
      *(float4*)(op + xcb) = *(float4*)&acc[mf][nf];
    }
  }
}

extern "C" void kernel_launch(void* const* d_in, const int* in_sizes, int n_in,
                              void* d_out, int out_size, void* d_ws, size_t ws_size,
                              hipStream_t stream) {
  (void)in_sizes; (void)n_in; (void)out_size; (void)ws_size;
  const float* x      = (const float*)d_in[0];
  const float* fc1    = (const float*)d_in[1];
  const float* fc2    = (const float*)d_in[2];
  const float* fc2b   = (const float*)d_in[3];
  const float* weight = (const float*)d_in[4];
  float* out = (float*)d_out;

  // workspace layout (~52.7 MB):
  //   [0,4K)            zero page (row-halo source for global_load_lds)
  //   [4K,20K)          pooled_sum f32[16][256]
  //   [20K, 86016)      prob f32[16][4][256]
  //   [131072, +18.87MB)  aggT bf16[16][9][256][256]
  //   [19,005,440, +33.55MB) x_nhwc bf16[16][64][64][256]
  char* ws = (char*)d_ws;
  unsigned short* zpage  = (unsigned short*)ws;
  float*          pooled = (float*)(ws + 4096);
  float*          prob   = (float*)(ws + 20480);
  unsigned short* aggT   = (unsigned short*)(ws + 131072);
  unsigned short* xnhwc  = (unsigned short*)(ws + 131072 + 18874368);

  hipMemsetAsync(d_ws, 0, 20480, stream);  // zero page + pooled_sum, every launch
  k_prep<<<dim3(16 * 64),  dim3(256), 0, stream>>>(x, xnhwc, pooled);
  k_fc  <<<dim3(16),       dim3(256), 0, stream>>>(pooled, fc1, fc2, fc2b, prob);
  k_agg <<<dim3(256),      dim3(256), 0, stream>>>(weight, prob, aggT);
  k_conv<<<dim3(1024),     dim3(256), 0, stream>>>(xnhwc, aggT, zpage, out);
}